// Round 5
// baseline (230.838 us; speedup 1.0000x reference)
//
#include <hip/hip_runtime.h>
#include <hip/hip_bf16.h>
#include <math.h>

#define T_ 4
#define B_ 8
#define C_ 256
#define HID_ 1024
#define E_ 8
#define K_ 2
#define HW_ 196
#define M_ 784            // T*HW rows per (b,expert) pair, r = hw*4 + t
#define NPAIR_ 16         // B*K active pairs
#define EPS_ 1e-5f

typedef __attribute__((ext_vector_type(8))) short bf16x8;
typedef __attribute__((ext_vector_type(8))) unsigned short u16x8;
typedef __attribute__((ext_vector_type(4))) float f32x4;

__device__ inline unsigned short f2bf(float f){
  union { float f; unsigned u; } v; v.f = f;
  unsigned u = v.u;
  unsigned r = u + 0x7FFFu + ((u >> 16) & 1u);   // RNE
  return (unsigned short)(r >> 16);
}
__device__ inline float bf2f(unsigned short h){
  union { unsigned u; float f; } v; v.u = ((unsigned)h) << 16;
  return v.f;
}

// split 8 f32 -> bf16 hi + bf16 lo (residual), all static-indexed
__device__ inline void split8(float4 v0, float4 v1, u16x8& hv, u16x8& lv){
  float f0=v0.x,f1=v0.y,f2=v0.z,f3=v0.w,f4=v1.x,f5=v1.y,f6=v1.z,f7=v1.w;
  unsigned short h;
  h=f2bf(f0); hv[0]=h; lv[0]=f2bf(f0-bf2f(h));
  h=f2bf(f1); hv[1]=h; lv[1]=f2bf(f1-bf2f(h));
  h=f2bf(f2); hv[2]=h; lv[2]=f2bf(f2-bf2f(h));
  h=f2bf(f3); hv[3]=h; lv[3]=f2bf(f3-bf2f(h));
  h=f2bf(f4); hv[4]=h; lv[4]=f2bf(f4-bf2f(h));
  h=f2bf(f5); hv[5]=h; lv[5]=f2bf(f5-bf2f(h));
  h=f2bf(f6); hv[6]=h; lv[6]=f2bf(f6-bf2f(h));
  h=f2bf(f7); hv[7]=h; lv[7]=f2bf(f7-bf2f(h));
}
__device__ inline u16x8 hi8(float4 v0, float4 v1){
  u16x8 hv;
  hv[0]=f2bf(v0.x); hv[1]=f2bf(v0.y); hv[2]=f2bf(v0.z); hv[3]=f2bf(v0.w);
  hv[4]=f2bf(v1.x); hv[5]=f2bf(v1.y); hv[6]=f2bf(v1.z); hv[7]=f2bf(v1.w);
  return hv;
}

// ---- xbar[b,c] = mean over (t,hw) of x ----
__global__ __launch_bounds__(64) void xbar_kernel(const float* __restrict__ x,
                                                  float* __restrict__ xbar){
  int bc = blockIdx.x;           // b*C + c
  int l = threadIdx.x;
  float s = 0.f;
  for (int t = 0; t < T_; t++){
    const float* p = x + ((size_t)(t * B_ * C_) + bc) * HW_;
    for (int i = l; i < HW_; i += 64) s += p[i];
  }
  for (int off = 32; off > 0; off >>= 1) s += __shfl_down(s, off, 64);
  if (l == 0) xbar[bc] = s * (1.0f / (T_ * HW_));
}

// ---- router: logits -> softmax -> top2 ----
__global__ __launch_bounds__(64) void router_kernel(const float* __restrict__ xbar,
    const float* __restrict__ rw, const float* __restrict__ rb,
    const float* __restrict__ rg, const float* __restrict__ rbb,
    const float* __restrict__ rm, const float* __restrict__ rv,
    int* __restrict__ sel_e, float* __restrict__ sel_w){
  __shared__ float lg[64];
  const int tid = threadIdx.x;
  const int b = tid >> 3, e = tid & 7;
  float dot = 0.f;
  for (int c = 0; c < C_; c++) dot += xbar[b * C_ + c] * rw[e * C_ + c];
  dot += rb[e];
  float sc = rg[e] / sqrtf(rv[e] + EPS_);
  lg[tid] = (dot - rm[e]) * sc + rbb[e];
  __syncthreads();
  if (e == 0){
    float l[E_], mx = -1e30f;
    for (int i = 0; i < E_; i++){ l[i] = lg[b * 8 + i]; mx = fmaxf(mx, l[i]); }
    float p[E_];
    for (int i = 0; i < E_; i++) p[i] = expf(l[i] - mx);
    int i1 = 0;
    for (int i = 1; i < E_; i++) if (p[i] > p[i1]) i1 = i;       // first index on ties
    int i2 = (i1 == 0) ? 1 : 0;
    for (int i = 0; i < E_; i++) if (i != i1 && p[i] > p[i2]) i2 = i;
    float denom = p[i1] + p[i2];
    sel_e[b * 2]     = i1; sel_w[b * 2]     = p[i1] / denom;
    sel_e[b * 2 + 1] = i2; sel_w[b * 2 + 1] = p[i2] / denom;
  }
}

// ---- LIF1: x -> s1 spikes (bf16 0/1), layout s1[pair][hw*4+t][c] ----
__global__ __launch_bounds__(256) void lif1_kernel(const float* __restrict__ x,
    const int* __restrict__ sel_e, const float* __restrict__ taus,
    unsigned short* __restrict__ s1){
  const int hw = blockIdx.x;      // 0..195
  const int pair = blockIdx.y;    // 0..15
  const int c = threadIdx.x;      // 0..255
  const int b = pair >> 1;
  const float tau = taus[sel_e[pair]];
  float v = 0.f;
  #pragma unroll
  for (int t = 0; t < T_; t++){
    float xv = x[((size_t)(t * B_ + b) * C_ + c) * HW_ + hw];
    float h = v + (xv - v) / tau;
    float s = (h >= 1.0f) ? 1.0f : 0.0f;
    v = h * (1.0f - s);
    s1[((size_t)pair * M_ + hw * 4 + t) * C_ + c] =
        (s > 0.5f) ? (unsigned short)0x3F80 : (unsigned short)0;
  }
}

// ---- GEMM1: block=(nhalf,mt,pair). A staged once (8 k-chunks), B (f32 w1)
// split hi/lo on the fly, double-buffered with register prefetch. BN1+LIF2
// epilogue per n-subtile, write s2 spikes. ----
__global__ __launch_bounds__(256) void g1_kernel(
    const unsigned short* __restrict__ s1,
    const float* __restrict__ w1,
    const float* __restrict__ fc1_b,
    const float* __restrict__ bn1_g, const float* __restrict__ bn1_b,
    const float* __restrict__ bn1_m, const float* __restrict__ bn1_v,
    const int* __restrict__ sel_e, const float* __restrict__ taus,
    unsigned short* __restrict__ s2)
{
  __shared__ __align__(16) unsigned short lA[8][64 * 40];   // 40 KB, whole K
  __shared__ __align__(16) unsigned short lBh[2][64 * 40];  // 10 KB dbuf
  __shared__ __align__(16) unsigned short lBl[2][64 * 40];  // 10 KB dbuf
  const int nhalf = blockIdx.x, mt = blockIdx.y, pair = blockIdx.z;
  const int e = sel_e[pair];
  const int m0 = mt * 64;
  const int tid = threadIdx.x;
  const int row = tid >> 2, seg = tid & 3;
  const int lane = tid & 63, wv = tid >> 6;
  const int koff = (lane >> 4) * 8;
  // ---- A prologue: all 8 k-chunks staged once ----
  {
    const unsigned short* s1p = s1 + (size_t)pair * (M_ * C_);
    const int r = m0 + row;
    #pragma unroll
    for (int ch = 0; ch < 8; ch++){
      u16x8 av = {};
      if (r < M_) av = *(const u16x8*)(s1p + (size_t)r * C_ + ch * 32 + seg * 8);
      *(u16x8*)(&lA[ch][row * 40 + seg * 8]) = av;
    }
  }
  const float* wp = w1 + ((size_t)e * HID_ + nhalf * 512 + row) * C_ + seg * 8;
  // ---- stage first B tile (nt=0,kk=0) ----
  {
    const float4* p = (const float4*)wp;
    float4 v0 = p[0], v1 = p[1];
    u16x8 hv, lv; split8(v0, v1, hv, lv);
    *(u16x8*)(&lBh[0][row * 40 + seg * 8]) = hv;
    *(u16x8*)(&lBl[0][row * 40 + seg * 8]) = lv;
  }
  __syncthreads();
  const float tau = taus[e];
  const int rbase = m0 + wv * 16 + ((lane >> 4) << 2);
  int cur = 0;
  for (int nt = 0; nt < 8; nt++){
    f32x4 acc[4] = {};
    for (int kk = 0; kk < 8; kk++){
      const int ii = nt * 8 + kk;
      const bool nx = (ii < 63);
      float4 v0, v1;
      if (nx){
        const int jj = ii + 1;
        const float4* p = (const float4*)(wp + (size_t)(jj >> 3) * 64 * C_ + (jj & 7) * 32);
        v0 = p[0]; v1 = p[1];               // issue early; consumed after MFMAs
      }
      bf16x8 a = *(const bf16x8*)(&lA[kk][(wv * 16 + (lane & 15)) * 40 + koff]);
      #pragma unroll
      for (int cb = 0; cb < 4; cb++){
        bf16x8 bh = *(const bf16x8*)(&lBh[cur][(cb * 16 + (lane & 15)) * 40 + koff]);
        bf16x8 bl = *(const bf16x8*)(&lBl[cur][(cb * 16 + (lane & 15)) * 40 + koff]);
        acc[cb] = __builtin_amdgcn_mfma_f32_16x16x32_bf16(a, bh, acc[cb], 0, 0, 0);
        acc[cb] = __builtin_amdgcn_mfma_f32_16x16x32_bf16(a, bl, acc[cb], 0, 0, 0);
      }
      if (nx){
        u16x8 hv, lv; split8(v0, v1, hv, lv);
        *(u16x8*)(&lBh[cur ^ 1][row * 40 + seg * 8]) = hv;
        *(u16x8*)(&lBl[cur ^ 1][row * 40 + seg * 8]) = lv;
      }
      if (kk == 7 && rbase < M_){
        // epilogue: lane holds t=0..3 of one (hw,col) -> in-register LIF
        #pragma unroll
        for (int cb = 0; cb < 4; cb++){
          int col = nhalf * 512 + nt * 64 + cb * 16 + (lane & 15);
          int pi = e * HID_ + col;
          float sc = bn1_g[pi] / sqrtf(bn1_v[pi] + EPS_);
          float mm = bn1_m[pi], bb = bn1_b[pi], cbias = fc1_b[pi];
          float v = 0.f;
          #pragma unroll
          for (int t = 0; t < 4; t++){
            float z = acc[cb][t] + cbias;
            float hin = (z - mm) * sc + bb;
            float h = v + (hin - v) / tau;
            float s = (h >= 1.0f) ? 1.0f : 0.0f;
            v = h * (1.0f - s);
            s2[((size_t)pair * M_ + rbase + t) * HID_ + col] =
                (s > 0.5f) ? (unsigned short)0x3F80 : (unsigned short)0;
          }
        }
      }
      __syncthreads();
      cur ^= 1;
    }
  }
}

// ---- GEMM2: block=(nt,mt,b), 2 slots inner. A(s2) + B(w2 f32 -> bf16 hi only,
// linear path tolerates it) double-buffered with register prefetch. ----
__global__ __launch_bounds__(256) void g2_kernel(
    const unsigned short* __restrict__ s2,
    const float* __restrict__ w2,
    const float* __restrict__ fc2_b,
    const float* __restrict__ bn2_g, const float* __restrict__ bn2_b,
    const float* __restrict__ bn2_m, const float* __restrict__ bn2_v,
    const int* __restrict__ sel_e, const float* __restrict__ sel_w,
    const float* __restrict__ x, float* __restrict__ out)
{
  __shared__ __align__(16) unsigned short lA[2][64 * 40];   // 10 KB
  __shared__ __align__(16) unsigned short lBh[2][64 * 40];  // 10 KB
  const int nt = blockIdx.x, mt = blockIdx.y, b = blockIdx.z;
  const int m0 = mt * 64, n0 = nt * 64;
  const int tid = threadIdx.x;
  const int row = tid >> 2, seg = tid & 3;
  const int lane = tid & 63, wv = tid >> 6;
  const int koff = (lane >> 4) * 8;
  const int r = m0 + row;
  f32x4 res[4] = {};
  for (int slot = 0; slot < 2; slot++){
    const int pair = b * 2 + slot;
    const int e = sel_e[pair];
    const float wgt = sel_w[pair];
    const unsigned short* s2p = s2 + (size_t)pair * (M_ * HID_) + (size_t)r * HID_ + seg * 8;
    const float* wp = w2 + ((size_t)e * C_ + n0 + row) * HID_ + seg * 8;
    // prologue kk=0
    {
      u16x8 av = {};
      if (r < M_) av = *(const u16x8*)s2p;
      const float4* p = (const float4*)wp;
      u16x8 hv = hi8(p[0], p[1]);
      *(u16x8*)(&lA[0][row * 40 + seg * 8]) = av;
      *(u16x8*)(&lBh[0][row * 40 + seg * 8]) = hv;
    }
    __syncthreads();
    f32x4 acc[4] = {};
    int cur = 0;
    for (int kk = 0; kk < 32; kk++){
      const bool nx = (kk < 31);
      u16x8 av = {};
      float4 v0, v1;
      if (nx){
        if (r < M_) av = *(const u16x8*)(s2p + (kk + 1) * 32);
        const float4* p = (const float4*)(wp + (kk + 1) * 32);
        v0 = p[0]; v1 = p[1];               // issue early
      }
      bf16x8 a = *(const bf16x8*)(&lA[cur][(wv * 16 + (lane & 15)) * 40 + koff]);
      #pragma unroll
      for (int cb = 0; cb < 4; cb++){
        bf16x8 bh = *(const bf16x8*)(&lBh[cur][(cb * 16 + (lane & 15)) * 40 + koff]);
        acc[cb] = __builtin_amdgcn_mfma_f32_16x16x32_bf16(a, bh, acc[cb], 0, 0, 0);
      }
      if (nx){
        u16x8 hv = hi8(v0, v1);
        *(u16x8*)(&lA[cur ^ 1][row * 40 + seg * 8]) = av;
        *(u16x8*)(&lBh[cur ^ 1][row * 40 + seg * 8]) = hv;
      }
      __syncthreads();
      cur ^= 1;
    }
    // fold this slot into res with BN2 + combine weight
    #pragma unroll
    for (int cb = 0; cb < 4; cb++){
      int col = n0 + cb * 16 + (lane & 15);
      int pi = e * C_ + col;
      float sc = bn2_g[pi] / sqrtf(bn2_v[pi] + EPS_);
      float mm = bn2_m[pi], bb = bn2_b[pi], cbias = fc2_b[pi];
      #pragma unroll
      for (int t = 0; t < 4; t++){
        float z = acc[cb][t] + cbias;
        float y = (z - mm) * sc + bb;
        res[cb][t] += wgt * y;
      }
    }
  }
  const int rbase = m0 + wv * 16 + ((lane >> 4) << 2);
  if (rbase < M_){
    const int hw = rbase >> 2;
    #pragma unroll
    for (int cb = 0; cb < 4; cb++){
      int col = n0 + cb * 16 + (lane & 15);
      #pragma unroll
      for (int t = 0; t < 4; t++){
        size_t oi = ((size_t)(t * B_ + b) * C_ + col) * HW_ + hw;
        out[oi] = x[oi] + res[cb][t];
      }
    }
  }
}

extern "C" void kernel_launch(void* const* d_in, const int* in_sizes, int n_in,
                              void* d_out, int out_size, void* d_ws, size_t ws_size,
                              hipStream_t stream){
  const float* x     = (const float*)d_in[0];
  const float* rw    = (const float*)d_in[1];
  const float* rb    = (const float*)d_in[2];
  const float* rg    = (const float*)d_in[3];
  const float* rbb   = (const float*)d_in[4];
  const float* rm    = (const float*)d_in[5];
  const float* rv    = (const float*)d_in[6];
  const float* fc1_w = (const float*)d_in[7];
  const float* fc1_b = (const float*)d_in[8];
  const float* bn1_g = (const float*)d_in[9];
  const float* bn1_b = (const float*)d_in[10];
  const float* bn1_m = (const float*)d_in[11];
  const float* bn1_v = (const float*)d_in[12];
  const float* fc2_w = (const float*)d_in[13];
  const float* fc2_b = (const float*)d_in[14];
  const float* bn2_g = (const float*)d_in[15];
  const float* bn2_b = (const float*)d_in[16];
  const float* bn2_m = (const float*)d_in[17];
  const float* bn2_v = (const float*)d_in[18];
  const float* taus  = (const float*)d_in[19];
  float* out = (float*)d_out;

  char* ws = (char*)d_ws;
  size_t off = 0;
  auto alloc = [&](size_t bytes) -> char* {
    char* p = ws + off;
    off = (off + bytes + 255) & ~(size_t)255;
    return p;
  };
  unsigned short* s1  = (unsigned short*)alloc((size_t)NPAIR_ * M_ * C_ * 2);    // 6.4 MB
  unsigned short* s2  = (unsigned short*)alloc((size_t)NPAIR_ * M_ * HID_ * 2);  // 25.7 MB
  float* xbar  = (float*)alloc(B_ * C_ * 4);
  int*   sel_e = (int*)alloc(NPAIR_ * 4);
  float* sel_w = (float*)alloc(NPAIR_ * 4);
  (void)ws_size; (void)in_sizes; (void)n_in; (void)out_size;

  xbar_kernel<<<B_ * C_, 64, 0, stream>>>(x, xbar);
  router_kernel<<<1, 64, 0, stream>>>(xbar, rw, rb, rg, rbb, rm, rv, sel_e, sel_w);
  lif1_kernel<<<dim3(HW_, NPAIR_), 256, 0, stream>>>(x, sel_e, taus, s1);
  g1_kernel<<<dim3(2, (M_ + 63) / 64, NPAIR_), 256, 0, stream>>>(
      s1, fc1_w, fc1_b, bn1_g, bn1_b, bn1_m, bn1_v, sel_e, taus, s2);
  g2_kernel<<<dim3(C_ / 64, (M_ + 63) / 64, B_), 256, 0, stream>>>(
      s2, fc2_w, fc2_b, bn2_g, bn2_b, bn2_m, bn2_v, sel_e, sel_w, x, out);
}

// Round 6
// 196.931 us; speedup vs baseline: 1.1722x; 1.1722x over previous
//
#include <hip/hip_runtime.h>
#include <hip/hip_bf16.h>
#include <math.h>

#define T_ 4
#define B_ 8
#define C_ 256
#define HID_ 1024
#define E_ 8
#define HW_ 196
#define M_ 784            // T*HW rows per (b,expert) pair, r = hw*4 + t
#define NPAIR_ 16
#define EPS_ 1e-5f
#define NOUT_ (T_*B_*C_*HW_)   // 1,605,632 floats

typedef __attribute__((ext_vector_type(8))) short bf16x8;
typedef __attribute__((ext_vector_type(4))) unsigned short u16x4;
typedef __attribute__((ext_vector_type(4))) float f32x4;

__device__ inline unsigned short f2bf(float f){
  union { float f; unsigned u; } v; v.f = f;
  unsigned u = v.u;
  unsigned r = u + 0x7FFFu + ((u >> 16) & 1u);   // RNE
  return (unsigned short)(r >> 16);
}
__device__ inline float bf2f(unsigned short h){
  union { unsigned u; float f; } v; v.u = ((unsigned)h) << 16;
  return v.f;
}

// direct global->LDS, 16B per lane; LDS dest = wave-uniform base + lane*16
__device__ inline void gl16(const void* g, void* l){
  auto gp = reinterpret_cast<const unsigned int __attribute__((address_space(1)))*>(
      reinterpret_cast<uintptr_t>(g));
  auto lp = reinterpret_cast<unsigned int __attribute__((address_space(3)))*>(
      reinterpret_cast<uintptr_t>(l));
  __builtin_amdgcn_global_load_lds(gp, lp, 16, 0, 0);
}

// ---- w1 -> bf16 hi + lo residual (once, memory-amortized) ----
__global__ __launch_bounds__(256) void wconv_hl_kernel(const float* __restrict__ w,
    unsigned short* __restrict__ hi, unsigned short* __restrict__ lo){
  int i = blockIdx.x * 256 + threadIdx.x;      // over NW/4
  float4 v = ((const float4*)w)[i];
  u16x4 h, l;
  h[0]=f2bf(v.x); l[0]=f2bf(v.x - bf2f(h[0]));
  h[1]=f2bf(v.y); l[1]=f2bf(v.y - bf2f(h[1]));
  h[2]=f2bf(v.z); l[2]=f2bf(v.z - bf2f(h[2]));
  h[3]=f2bf(v.w); l[3]=f2bf(v.w - bf2f(h[3]));
  ((u16x4*)hi)[i] = h; ((u16x4*)lo)[i] = l;
}
// ---- w2 -> bf16 hi only (linear output path tolerates it) ----
__global__ __launch_bounds__(256) void wconv_h_kernel(const float* __restrict__ w,
    unsigned short* __restrict__ hi){
  int i = blockIdx.x * 256 + threadIdx.x;
  float4 v = ((const float4*)w)[i];
  u16x4 h;
  h[0]=f2bf(v.x); h[1]=f2bf(v.y); h[2]=f2bf(v.z); h[3]=f2bf(v.w);
  ((u16x4*)hi)[i] = h;
}

// ---- xbar[b,c] = mean over (t,hw) of x ----
__global__ __launch_bounds__(64) void xbar_kernel(const float* __restrict__ x,
                                                  float* __restrict__ xbar){
  int bc = blockIdx.x;
  int l = threadIdx.x;
  float s = 0.f;
  for (int t = 0; t < T_; t++){
    const float* p = x + ((size_t)(t * B_ * C_) + bc) * HW_;
    for (int i = l; i < HW_; i += 64) s += p[i];
  }
  for (int off = 32; off > 0; off >>= 1) s += __shfl_down(s, off, 64);
  if (l == 0) xbar[bc] = s * (1.0f / (T_ * HW_));
}

// ---- router: logits -> softmax -> top2 ----
__global__ __launch_bounds__(64) void router_kernel(const float* __restrict__ xbar,
    const float* __restrict__ rw, const float* __restrict__ rb,
    const float* __restrict__ rg, const float* __restrict__ rbb,
    const float* __restrict__ rm, const float* __restrict__ rv,
    int* __restrict__ sel_e, float* __restrict__ sel_w){
  __shared__ float lg[64];
  const int tid = threadIdx.x;
  const int b = tid >> 3, e = tid & 7;
  float dot = 0.f;
  for (int c = 0; c < C_; c++) dot += xbar[b * C_ + c] * rw[e * C_ + c];
  dot += rb[e];
  float sc = rg[e] / sqrtf(rv[e] + EPS_);
  lg[tid] = (dot - rm[e]) * sc + rbb[e];
  __syncthreads();
  if (e == 0){
    float l[E_], mx = -1e30f;
    for (int i = 0; i < E_; i++){ l[i] = lg[b * 8 + i]; mx = fmaxf(mx, l[i]); }
    float p[E_];
    for (int i = 0; i < E_; i++) p[i] = expf(l[i] - mx);
    int i1 = 0;
    for (int i = 1; i < E_; i++) if (p[i] > p[i1]) i1 = i;
    int i2 = (i1 == 0) ? 1 : 0;
    for (int i = 0; i < E_; i++) if (i != i1 && p[i] > p[i2]) i2 = i;
    float denom = p[i1] + p[i2];
    sel_e[b * 2]     = i1; sel_w[b * 2]     = p[i1] / denom;
    sel_e[b * 2 + 1] = i2; sel_w[b * 2 + 1] = p[i2] / denom;
  }
}

// ---- LIF1: x -> s1 spikes, layout s1[pair][hw*4+t][c] ----
__global__ __launch_bounds__(256) void lif1_kernel(const float* __restrict__ x,
    const int* __restrict__ sel_e, const float* __restrict__ taus,
    unsigned short* __restrict__ s1){
  const int hw = blockIdx.x;
  const int pair = blockIdx.y;
  const int c = threadIdx.x;
  const int b = pair >> 1;
  const float tau = taus[sel_e[pair]];
  float v = 0.f;
  #pragma unroll
  for (int t = 0; t < T_; t++){
    float xv = x[((size_t)(t * B_ + b) * C_ + c) * HW_ + hw];
    float h = v + (xv - v) / tau;
    float s = (h >= 1.0f) ? 1.0f : 0.0f;
    v = h * (1.0f - s);
    s1[((size_t)pair * M_ + hw * 4 + t) * C_ + c] =
        (s > 0.5f) ? (unsigned short)0x3F80 : (unsigned short)0;
  }
}

// ---- GEMM1: grid (nt16, mt13, pair16); 24KB LDS dbuf; gl16 staging;
// hi/lo MFMA; BN1+LIF2 in-register epilogue -> s2 ----
__global__ __launch_bounds__(256) void g1_kernel(
    const unsigned short* __restrict__ s1,
    const unsigned short* __restrict__ w1h, const unsigned short* __restrict__ w1l,
    const float* __restrict__ fc1_b,
    const float* __restrict__ bn1_g, const float* __restrict__ bn1_b,
    const float* __restrict__ bn1_m, const float* __restrict__ bn1_v,
    const int* __restrict__ sel_e, const float* __restrict__ taus,
    unsigned short* __restrict__ s2)
{
  __shared__ __align__(16) unsigned short lA[2][2048];   // [64][32] per buf
  __shared__ __align__(16) unsigned short lBh[2][2048];
  __shared__ __align__(16) unsigned short lBl[2][2048];
  const int nt = blockIdx.x, mt = blockIdx.y, pair = blockIdx.z;
  const int e = sel_e[pair];
  const int m0 = mt * 64, n0 = nt * 64;
  const int tid = threadIdx.x, lane = tid & 63, wv = tid >> 6;
  const int l15 = lane & 15, koff = (lane >> 4) * 8;
  // staging: wave wv covers 16 rows; lane i -> row wv*16+(i>>2), 16B col (i&3)
  const int srow = wv * 16 + (lane >> 2);
  const int scol = (lane & 3) * 8;
  int arow = m0 + srow; if (arow > M_ - 1) arow = M_ - 1;   // clamp: dup row, discarded
  const unsigned short* aG  = s1  + ((size_t)pair * M_ + arow) * C_ + scol;
  const unsigned short* bhG = w1h + ((size_t)e * HID_ + n0 + srow) * C_ + scol;
  const unsigned short* blG = w1l + ((size_t)e * HID_ + n0 + srow) * C_ + scol;
  const int lb = wv * 512;                                  // u16 units = wv*1024B
  gl16(aG,  &lA[0][lb]);
  gl16(bhG, &lBh[0][lb]);
  gl16(blG, &lBl[0][lb]);
  __syncthreads();
  f32x4 acc[4] = {};
  for (int kk = 0; kk < 8; kk++){
    const int cur = kk & 1, nxt = cur ^ 1;
    if (kk < 7){
      gl16(aG  + (kk + 1) * 32, &lA[nxt][lb]);
      gl16(bhG + (kk + 1) * 32, &lBh[nxt][lb]);
      gl16(blG + (kk + 1) * 32, &lBl[nxt][lb]);
    }
    bf16x8 a = *(const bf16x8*)(&lA[cur][(wv * 16 + l15) * 32 + koff]);
    #pragma unroll
    for (int cb = 0; cb < 4; cb++){
      bf16x8 bh = *(const bf16x8*)(&lBh[cur][(cb * 16 + l15) * 32 + koff]);
      bf16x8 bl = *(const bf16x8*)(&lBl[cur][(cb * 16 + l15) * 32 + koff]);
      acc[cb] = __builtin_amdgcn_mfma_f32_16x16x32_bf16(a, bh, acc[cb], 0, 0, 0);
      acc[cb] = __builtin_amdgcn_mfma_f32_16x16x32_bf16(a, bl, acc[cb], 0, 0, 0);
    }
    __syncthreads();   // drains vmcnt: next-buf gl16 loads landed
  }
  const float tau = taus[e];
  const int rbase = m0 + wv * 16 + ((lane >> 4) << 2);
  if (rbase < M_){
    #pragma unroll
    for (int cb = 0; cb < 4; cb++){
      int col = n0 + cb * 16 + l15;
      int pi = e * HID_ + col;
      float sc = bn1_g[pi] / sqrtf(bn1_v[pi] + EPS_);
      float mm = bn1_m[pi], bb = bn1_b[pi], cbias = fc1_b[pi];
      float v = 0.f;
      #pragma unroll
      for (int t = 0; t < 4; t++){
        float z = acc[cb][t] + cbias;
        float hin = (z - mm) * sc + bb;
        float h = v + (hin - v) / tau;
        float s = (h >= 1.0f) ? 1.0f : 0.0f;
        v = h * (1.0f - s);
        s2[((size_t)pair * M_ + rbase + t) * HID_ + col] =
            (s > 0.5f) ? (unsigned short)0x3F80 : (unsigned short)0;
      }
    }
  }
}

// ---- GEMM2: grid (nt4, mt13, pair16); one pair per block; hi-only;
// writes weighted BN2 output to y[slot] in out-layout ----
__global__ __launch_bounds__(256) void g2_kernel(
    const unsigned short* __restrict__ s2,
    const unsigned short* __restrict__ w2h,
    const float* __restrict__ fc2_b,
    const float* __restrict__ bn2_g, const float* __restrict__ bn2_b,
    const float* __restrict__ bn2_m, const float* __restrict__ bn2_v,
    const int* __restrict__ sel_e, const float* __restrict__ sel_w,
    float* __restrict__ y)
{
  __shared__ __align__(16) unsigned short lA[2][2048];
  __shared__ __align__(16) unsigned short lBh[2][2048];
  const int nt = blockIdx.x, mt = blockIdx.y, pair = blockIdx.z;
  const int e = sel_e[pair];
  const float wgt = sel_w[pair];
  const int b = pair >> 1, slot = pair & 1;
  const int m0 = mt * 64, n0 = nt * 64;
  const int tid = threadIdx.x, lane = tid & 63, wv = tid >> 6;
  const int l15 = lane & 15, koff = (lane >> 4) * 8;
  const int srow = wv * 16 + (lane >> 2);
  const int scol = (lane & 3) * 8;
  int arow = m0 + srow; if (arow > M_ - 1) arow = M_ - 1;
  const unsigned short* aG  = s2  + ((size_t)pair * M_ + arow) * HID_ + scol;
  const unsigned short* bhG = w2h + ((size_t)e * C_ + n0 + srow) * HID_ + scol;
  const int lb = wv * 512;
  gl16(aG,  &lA[0][lb]);
  gl16(bhG, &lBh[0][lb]);
  __syncthreads();
  f32x4 acc[4] = {};
  for (int kk = 0; kk < 32; kk++){
    const int cur = kk & 1, nxt = cur ^ 1;
    if (kk < 31){
      gl16(aG  + (kk + 1) * 32, &lA[nxt][lb]);
      gl16(bhG + (kk + 1) * 32, &lBh[nxt][lb]);
    }
    bf16x8 a = *(const bf16x8*)(&lA[cur][(wv * 16 + l15) * 32 + koff]);
    #pragma unroll
    for (int cb = 0; cb < 4; cb++){
      bf16x8 bh = *(const bf16x8*)(&lBh[cur][(cb * 16 + l15) * 32 + koff]);
      acc[cb] = __builtin_amdgcn_mfma_f32_16x16x32_bf16(a, bh, acc[cb], 0, 0, 0);
    }
    __syncthreads();
  }
  const int rbase = m0 + wv * 16 + ((lane >> 4) << 2);
  if (rbase < M_){
    const int hw = rbase >> 2;
    #pragma unroll
    for (int cb = 0; cb < 4; cb++){
      int col = n0 + cb * 16 + l15;
      int pi = e * C_ + col;
      float sc = bn2_g[pi] / sqrtf(bn2_v[pi] + EPS_);
      float mm = bn2_m[pi], bb = bn2_b[pi], cbias = fc2_b[pi];
      #pragma unroll
      for (int t = 0; t < 4; t++){
        float z = acc[cb][t] + cbias;
        float yv = (z - mm) * sc + bb;
        y[(((size_t)slot * T_ + t) * B_ + b) * (C_ * HW_) + (size_t)col * HW_ + hw] =
            wgt * yv;
      }
    }
  }
}

// ---- out = x + y0 + y1 (fully coalesced float4) ----
__global__ __launch_bounds__(256) void combine_kernel(const float* __restrict__ x,
    const float* __restrict__ y, float* __restrict__ out){
  int i = blockIdx.x * 256 + threadIdx.x;      // over NOUT_/4
  float4 a  = ((const float4*)x)[i];
  float4 b0 = ((const float4*)y)[i];
  float4 b1 = ((const float4*)y)[i + NOUT_ / 4];
  float4 r;
  r.x = a.x + b0.x + b1.x;
  r.y = a.y + b0.y + b1.y;
  r.z = a.z + b0.z + b1.z;
  r.w = a.w + b0.w + b1.w;
  ((float4*)out)[i] = r;
}

extern "C" void kernel_launch(void* const* d_in, const int* in_sizes, int n_in,
                              void* d_out, int out_size, void* d_ws, size_t ws_size,
                              hipStream_t stream){
  const float* x     = (const float*)d_in[0];
  const float* rw    = (const float*)d_in[1];
  const float* rb    = (const float*)d_in[2];
  const float* rg    = (const float*)d_in[3];
  const float* rbb   = (const float*)d_in[4];
  const float* rm    = (const float*)d_in[5];
  const float* rv    = (const float*)d_in[6];
  const float* fc1_w = (const float*)d_in[7];
  const float* fc1_b = (const float*)d_in[8];
  const float* bn1_g = (const float*)d_in[9];
  const float* bn1_b = (const float*)d_in[10];
  const float* bn1_m = (const float*)d_in[11];
  const float* bn1_v = (const float*)d_in[12];
  const float* fc2_w = (const float*)d_in[13];
  const float* fc2_b = (const float*)d_in[14];
  const float* bn2_g = (const float*)d_in[15];
  const float* bn2_b = (const float*)d_in[16];
  const float* bn2_m = (const float*)d_in[17];
  const float* bn2_v = (const float*)d_in[18];
  const float* taus  = (const float*)d_in[19];
  float* out = (float*)d_out;

  char* ws = (char*)d_ws;
  size_t off = 0;
  auto alloc = [&](size_t bytes) -> char* {
    char* p = ws + off;
    off = (off + bytes + 255) & ~(size_t)255;
    return p;
  };
  const int NW = E_ * HID_ * C_;                                   // 2,097,152
  unsigned short* s2  = (unsigned short*)alloc((size_t)NPAIR_ * M_ * HID_ * 2); // 25.7MB
  unsigned short* w2h = (unsigned short*)alloc((size_t)NW * 2);                 // 4.2MB
  unsigned short* w1h = (unsigned short*)alloc((size_t)NW * 2);                 // 4.2MB
  unsigned short* w1l = (unsigned short*)alloc((size_t)NW * 2);                 // 4.2MB
  unsigned short* s1  = (unsigned short*)alloc((size_t)NPAIR_ * M_ * C_ * 2);   // 6.4MB
  float* xbar  = (float*)alloc(B_ * C_ * 4);
  int*   sel_e = (int*)alloc(NPAIR_ * 4);
  float* sel_w = (float*)alloc(NPAIR_ * 4);
  // y (2 slots, out-layout, f32 = 12.8MB) overlays w1h+w1l+s1 (14.8MB):
  // dead after g1 completes, rewritten by wconv/lif1 every call.
  float* y = (float*)w1h;
  (void)ws_size; (void)in_sizes; (void)n_in; (void)out_size;

  wconv_hl_kernel<<<NW / 4 / 256, 256, 0, stream>>>(fc1_w, w1h, w1l);
  wconv_h_kernel <<<NW / 4 / 256, 256, 0, stream>>>(fc2_w, w2h);
  xbar_kernel<<<B_ * C_, 64, 0, stream>>>(x, xbar);
  router_kernel<<<1, 64, 0, stream>>>(xbar, rw, rb, rg, rbb, rm, rv, sel_e, sel_w);
  lif1_kernel<<<dim3(HW_, NPAIR_), 256, 0, stream>>>(x, sel_e, taus, s1);
  g1_kernel<<<dim3(HID_ / 64, (M_ + 63) / 64, NPAIR_), 256, 0, stream>>>(
      s1, w1h, w1l, fc1_b, bn1_g, bn1_b, bn1_m, bn1_v, sel_e, taus, s2);
  g2_kernel<<<dim3(C_ / 64, (M_ + 63) / 64, NPAIR_), 256, 0, stream>>>(
      s2, w2h, fc2_b, bn2_g, bn2_b, bn2_m, bn2_v, sel_e, sel_w, y);
  combine_kernel<<<NOUT_ / 4 / 256, 256, 0, stream>>>(x, y, out);
}